// Round 4
// baseline (246.170 us; speedup 1.0000x reference)
//
#include <hip/hip_runtime.h>

// DenseDilatedKnnGraphDGL: B=64, C=256, N=1024, layer_idx=8 -> dilation=3, k=9, k_d=27
// out[0:589824]       = src_d (int32): rank-{0,3,..,24} neighbor index + b*N
// out[589824:1179648] = dst_d (int32): j/9
//
// R11 (fixes R10's three regressions, keeps the halved-LDS-read algorithm):
//  - __launch_bounds__(256,4): R10's (256,3) dropped occupancy to 24.5% for
//    nothing (compiled at 84 VGPR << 128 cap). 4 blocks/CU restores TLP that
//    hides per-chunk stage latency.
//  - inline-asm v_med3_u32 REMOVED: umax_(p, umin_(q, cur)) is the med3 idiom
//    the compiler pattern-matches natively; 40 asm blocks/chunk were a
//    scheduling pessimization.
//  - epilogue: M (own-qset lists) copied out of L0/L1 BEFORE the LDS exchange
//    store, so L dies at the store -> no live-across-barrier spill (R10 showed
//    +6MB scratch WRITE_SIZE).
//  - algorithm unchanged from R10: 2 A-sets/wave over half the points; every
//    ds_read_b128 feeds 2 MFMAs (grid ds_reads 2^20, conflicts 4.19M);
//    partner-wave keep-5 list exchange + exact merge network.

typedef __bf16 bf16x8 __attribute__((ext_vector_type(8)));
typedef float  f32x4  __attribute__((ext_vector_type(4)));
typedef unsigned int u32;

#define B_   64
#define C_   256
#define N_   1024
#define NSRC (B_ * N_ * 9)   // 589824

#define STRIDE_I 1088        // 1024 + 64B pad between staging instructions
#define BUFB     17408       // 16 * STRIDE_I = one 32-row chunk buffer
#define INF_     0xFFFFFFFFu

__device__ __forceinline__ u32 umin_(u32 a, u32 b) { return a < b ? a : b; }
__device__ __forceinline__ u32 umax_(u32 a, u32 b) { return a > b ? a : b; }

__device__ __forceinline__ void load_lds16(const void* g, void* l) {
    __builtin_amdgcn_global_load_lds((const __attribute__((address_space(1))) void*)g,
                                     (__attribute__((address_space(3))) void*)l,
                                     16, 0, 0);
}

// keep-5 ascending insert, parallel med3-idiom form (compiler emits v_med3_u32)
#define INS5(Ls, cur_)                                                        \
    do {                                                                      \
        u32 p0 = Ls[0], p1 = Ls[1], p2 = Ls[2], p3 = Ls[3], p4 = Ls[4];       \
        Ls[0] = umin_(p0, cur_);                                              \
        Ls[1] = umax_(p0, umin_(p1, cur_));                                   \
        Ls[2] = umax_(p1, umin_(p2, cur_));                                   \
        Ls[3] = umax_(p2, umin_(p3, cur_));                                   \
        Ls[4] = umax_(p3, umin_(p4, cur_));                                   \
    } while (0)

// ---------------------------------------------------------------------------
// Kernel 1: transpose + fp32->bf16 + row norms (bf16-consistent), +512 shift.
// grid 1024 = 64 b x 16 n-chunks of 64; block 256.
__global__ __launch_bounds__(256, 4) void trans_kernel(const float* __restrict__ X,
                                                       unsigned short* __restrict__ XT,
                                                       float* __restrict__ NRM) {
    __shared__ u32 T2[128][68];   // [c-pair][n_local], 34816 B; 68 -> 16B-aligned rows
    const int tid = threadIdx.x;
    const int b   = blockIdx.x >> 4;
    const int n0  = (blockIdx.x & 15) * 64;

    // ---- Phase A ----
    {
        const int cpl = tid >> 4;        // 0..15
        const int s   = tid & 15;        // n quad slot
#pragma unroll
        for (int it = 0; it < 8; ++it) {
            const int c0 = it * 32 + cpl * 2;
            const float* src = X + ((size_t)b * C_ + c0) * N_ + n0 + s * 4;
            float4 f0 = *(const float4*)(src);
            float4 f1 = *(const float4*)(src + N_);
            const float a0[4] = {f0.x, f0.y, f0.z, f0.w};
            const float a1[4] = {f1.x, f1.y, f1.z, f1.w};
            u32 pk[4];
#pragma unroll
            for (int j = 0; j < 4; ++j) {
                u32 u0 = __float_as_uint(a0[j]);
                u32 u1 = __float_as_uint(a1[j]);
                u32 b0 = (u0 + 0x7FFFu + ((u0 >> 16) & 1u)) >> 16;   // RNE
                u32 b1 = (u1 + 0x7FFFu + ((u1 >> 16) & 1u)) >> 16;
                pk[j] = b0 | (b1 << 16);
            }
            *(uint4*)&T2[it * 16 + cpl][s * 4] = make_uint4(pk[0], pk[1], pk[2], pk[3]);
        }
    }
    __syncthreads();

    // ---- Phase B ----
    {
        const int rr = tid >> 2, p = tid & 3;
        unsigned short* xtrow = XT + ((size_t)b * N_ + n0 + rr) * C_;
        float nsq = 0.f;
#pragma unroll
        for (int j = 0; j < 8; ++j) {
            u32 x0 = T2[j * 16 + 4 * p + 0][rr];
            u32 x1 = T2[j * 16 + 4 * p + 1][rr];
            u32 x2 = T2[j * 16 + 4 * p + 2][rr];
            u32 x3 = T2[j * 16 + 4 * p + 3][rr];
            const u32 xs[4] = {x0, x1, x2, x3};
#pragma unroll
            for (int q = 0; q < 4; ++q) {
                float lo = __uint_as_float(xs[q] << 16);
                float hi = __uint_as_float(xs[q] & 0xFFFF0000u);
                nsq = fmaf(lo, lo, fmaf(hi, hi, nsq));
            }
            *(uint4*)((char*)xtrow + j * 64 + p * 16) = make_uint4(x0, x1, x2, x3);
        }
        nsq += __shfl_xor(nsq, 1);
        nsq += __shfl_xor(nsq, 2);
        // +512 shift: f = nrm - 2*dot strictly positive for every query
        // -> float bits directly uint-monotone, no sign-flip transform.
        if (p == 0) NRM[b * N_ + n0 + rr] = nsq + 512.0f;
    }
}

// ---------------------------------------------------------------------------
// bitonic-merge of a bitonic 8-seq in regs -> ascending (phases j=4,2,1)
#define SORT8(v)                                                              \
    do {                                                                      \
        u32 mn, mx;                                                           \
        mn = umin_(v[0], v[4]); mx = umax_(v[0], v[4]); v[0] = mn; v[4] = mx; \
        mn = umin_(v[1], v[5]); mx = umax_(v[1], v[5]); v[1] = mn; v[5] = mx; \
        mn = umin_(v[2], v[6]); mx = umax_(v[2], v[6]); v[2] = mn; v[6] = mx; \
        mn = umin_(v[3], v[7]); mx = umax_(v[3], v[7]); v[3] = mn; v[7] = mx; \
        mn = umin_(v[0], v[2]); mx = umax_(v[0], v[2]); v[0] = mn; v[2] = mx; \
        mn = umin_(v[1], v[3]); mx = umax_(v[1], v[3]); v[1] = mn; v[3] = mx; \
        mn = umin_(v[4], v[6]); mx = umax_(v[4], v[6]); v[4] = mn; v[6] = mx; \
        mn = umin_(v[5], v[7]); mx = umax_(v[5], v[7]); v[5] = mn; v[7] = mx; \
        mn = umin_(v[0], v[1]); mx = umax_(v[0], v[1]); v[0] = mn; v[1] = mx; \
        mn = umin_(v[2], v[3]); mx = umax_(v[2], v[3]); v[2] = mn; v[3] = mx; \
        mn = umin_(v[4], v[5]); mx = umax_(v[4], v[5]); v[4] = mn; v[5] = mx; \
        mn = umin_(v[6], v[7]); mx = umax_(v[6], v[7]); v[6] = mn; v[7] = mx; \
    } while (0)

// Kernel 2: MFMA distances; 2 query-sets/wave, half-point-tile/wave.
// grid 1024 = 64 b x 16 query-chunks of 64; block 256 (4 waves); 4 blocks/CU.
__global__ __launch_bounds__(256, 4) void knn_mfma_kernel(const unsigned short* __restrict__ XT,
                                                          const float* __restrict__ NRM,
                                                          int* __restrict__ out) {
    __shared__ __align__(1024) char Bt[2 * BUFB];   // 34816 B (2 chunk buffers)

    const int tid  = threadIdx.x;
    const int lane = tid & 63;
    const int w    = tid >> 6;
    const int qpair = w >> 1;   // which 32-query group
    const int h     = w & 1;    // which 16-point half of each chunk

    const int bi = blockIdx.x;
    const int b  = (bi & 7) + 8 * (bi >> 7);     // batch-locality swizzle (mod-8)
    const int n0 = ((bi >> 3) & 15) * 64;        // query base (64 queries/block)

    const int lrow = lane & 15;
    const int g    = lane >> 4;
    const bool odd = lane & 1;
    const bool hiP = (lane >> 1) & 1;

    const unsigned short* xtb = XT + (size_t)b * N_ * C_;
    const char* xtc = (const char*)xtb;
    const float* nrmb = NRM + b * N_;

    // A fragments: 2 sets x 8 kc (wave's 32 queries, full K=256) -- 64 VGPRs
    bf16x8 afr0[8], afr1[8];
    {
        const unsigned short* ap0 = xtb + (n0 + qpair * 32 + lrow) * C_ + g * 8;
        const unsigned short* ap1 = ap0 + 16 * C_;
#pragma unroll
        for (int kc = 0; kc < 8; ++kc) afr0[kc] = *(const bf16x8*)(ap0 + kc * 32);
#pragma unroll
        for (int kc = 0; kc < 8; ++kc) afr1[kc] = *(const bf16x8*)(ap1 + kc * 32);
    }

    // per-(qset,row) per-lane sorted top-5 lists (ascending) -- 40 VGPRs
    u32 L0[4][5], L1[4][5];
#pragma unroll
    for (int r = 0; r < 4; ++r)
#pragma unroll
        for (int i = 0; i < 5; ++i) { L0[r][i] = INF_; L1[r][i] = INF_; }

    // loop-invariant LDS read offsets (rotation folded in), 8 VGPRs
    u32 roffv[8];
#pragma unroll
    for (int kc = 0; kc < 8; ++kc)
        roffv[kc] = (u32)(h * 8704 + (lrow >> 1) * STRIDE_I + (lrow & 1) * 512 +
                          ((kc * 64 + (g + lrow) * 16) & 511));

    // staging source voffsets (per-lane, 32-bit); dest is linear per wave
    const int lh   = lane >> 5;
    const int col0 = (lane & 31) * 16;
    u32 voff[4];
#pragma unroll
    for (int i = 0; i < 4; ++i) {
        const int rt  = i * 2 + lh;                           // row within wave's 8
        const int col = (col0 - (((w * 8 + rt) & 15) * 16)) & 511;
        voff[i] = (u32)((w * 8 + rt) * 512 + col);            // chunk 0
    }
    const float* nmp = nrmb + h * 16 + lrow;                  // per-lane norm ptr

    // ---- prologue: stage chunk 0 into buffer 0 ----
#pragma unroll
    for (int i = 0; i < 4; ++i)
        load_lds16(xtc + voff[i], Bt + (w * 4 + i) * STRIDE_I);
#pragma unroll
    for (int i = 0; i < 4; ++i) voff[i] += 16384;             // -> chunk 1
    __syncthreads();

#pragma unroll 1
    for (int cp = 0; cp < 16; ++cp) {
        const int c0v = cp * 2;

        // ================= chunk A: c = c0v (even), reads buf0 =============
        {
            const float nm = nmp[c0v * 32];
            // prefetch c0v+1 into buf1 (always valid: c0v+1 <= 31)
#pragma unroll
            for (int i = 0; i < 4; ++i)
                load_lds16(xtc + voff[i], Bt + BUFB + (w * 4 + i) * STRIDE_I);
#pragma unroll
            for (int i = 0; i < 4; ++i) voff[i] += 16384;

            f32x4 acc0 = {0.f, 0.f, 0.f, 0.f};
            f32x4 acc1 = {0.f, 0.f, 0.f, 0.f};
#pragma unroll
            for (int kc = 0; kc < 8; ++kc) {
                bf16x8 bfr = *(const bf16x8*)(Bt + roffv[kc]);
                acc0 = __builtin_amdgcn_mfma_f32_16x16x32_bf16(afr0[kc], bfr, acc0, 0, 0, 0);
                acc1 = __builtin_amdgcn_mfma_f32_16x16x32_bf16(afr1[kc], bfr, acc1, 0, 0, 0);
            }
            const u32 m = (u32)(c0v * 32 + h * 16 + lrow);
#pragma unroll
            for (int r = 0; r < 4; ++r) {
                float f = fmaf(-2.f, acc0[r], nm);            // > 0 (NRM has +512)
                u32 cur = (__float_as_uint(f) & 0xFFFFFC00u) | m;
                INS5(L0[r], cur);
            }
#pragma unroll
            for (int r = 0; r < 4; ++r) {
                float f = fmaf(-2.f, acc1[r], nm);
                u32 cur = (__float_as_uint(f) & 0xFFFFFC00u) | m;
                INS5(L1[r], cur);
            }
            __syncthreads();   // publishes buf1, releases buf0
        }

        // ================= chunk B: c = c0v+1 (odd), reads buf1 ============
        {
            const float nm = nmp[c0v * 32 + 32];
            if (cp < 15) {     // prefetch c0v+2 into buf0
#pragma unroll
                for (int i = 0; i < 4; ++i)
                    load_lds16(xtc + voff[i], Bt + (w * 4 + i) * STRIDE_I);
#pragma unroll
                for (int i = 0; i < 4; ++i) voff[i] += 16384;
            }

            f32x4 acc0 = {0.f, 0.f, 0.f, 0.f};
            f32x4 acc1 = {0.f, 0.f, 0.f, 0.f};
#pragma unroll
            for (int kc = 0; kc < 8; ++kc) {
                bf16x8 bfr = *(const bf16x8*)(Bt + BUFB + roffv[kc]);
                acc0 = __builtin_amdgcn_mfma_f32_16x16x32_bf16(afr0[kc], bfr, acc0, 0, 0, 0);
                acc1 = __builtin_amdgcn_mfma_f32_16x16x32_bf16(afr1[kc], bfr, acc1, 0, 0, 0);
            }
            const u32 m = (u32)(c0v * 32 + 32 + h * 16 + lrow);
#pragma unroll
            for (int r = 0; r < 4; ++r) {
                float f = fmaf(-2.f, acc0[r], nm);
                u32 cur = (__float_as_uint(f) & 0xFFFFFC00u) | m;
                INS5(L0[r], cur);
            }
#pragma unroll
            for (int r = 0; r < 4; ++r) {
                float f = fmaf(-2.f, acc1[r], nm);
                u32 cur = (__float_as_uint(f) & 0xFFFFFC00u) | m;
                INS5(L1[r], cur);
            }
            __syncthreads();   // publishes buf0 (next A), releases buf1
        }
    }

    // ---- exchange: partner waves (w^1) cover the other point half ----
    // Copy own-output lists (qset h) out of L FIRST so L0/L1 die at the store
    // below (no live-across-barrier register pressure).
    u32 M[4][5];
#pragma unroll
    for (int r = 0; r < 4; ++r)
#pragma unroll
        for (int j = 0; j < 5; ++j) M[r][j] = h ? L1[r][j] : L0[r][j];

    // wave outputs qset h; hands its lists for qset h^1 to the partner.
    {
        const u32 mybase = (u32)((w * 64 + lane) * 80);
        if (h == 0) {
#pragma unroll
            for (int j = 0; j < 5; ++j)
                *(uint4*)(Bt + mybase + j * 16) =
                    make_uint4(L1[0][j], L1[1][j], L1[2][j], L1[3][j]);
        } else {
#pragma unroll
            for (int j = 0; j < 5; ++j)
                *(uint4*)(Bt + mybase + j * 16) =
                    make_uint4(L0[0][j], L0[1][j], L0[2][j], L0[3][j]);
        }
    }
    __syncthreads();
    u32 P[4][5];
    {
        const u32 exbase = (u32)(((w ^ 1) * 64 + lane) * 80);
#pragma unroll
        for (int j = 0; j < 5; ++j) {
            uint4 q = *(const uint4*)(Bt + exbase + j * 16);
            P[0][j] = q.x; P[1][j] = q.y; P[2][j] = q.z; P[3][j] = q.w;
        }
    }

    // ---- selection: exact distributed top-32 per query row (row = 4g+r) ----
    int* out_src = out;
    int* out_dst = out + NSRC;
#pragma unroll
    for (int r = 0; r < 4; ++r) {
        u32 v[8], t1[8];
        // merge own keep-5 with partner keep-5 -> sorted top-8/lane
        {
            u32 a[8], t[8];
#pragma unroll
            for (int i = 0; i < 5; ++i) { a[i] = M[r][i]; t[i] = P[r][i]; }
            a[5] = a[6] = a[7] = INF_;
            t[5] = t[6] = t[7] = INF_;
#pragma unroll
            for (int i = 0; i < 8; ++i) v[i] = umin_(a[i], t[7 - i]);
            SORT8(v);
        }

        // S1: pair merge, keep all 16 (e: ranks 0-7, o: 8-15)
#pragma unroll
        for (int i = 0; i < 8; ++i) t1[i] = __shfl_xor(v[i], 1);
#pragma unroll
        for (int i = 0; i < 8; ++i) {
            u32 mn = umin_(v[i], t1[7 - i]);
            u32 mx = umax_(v[i], t1[7 - i]);
            v[i] = odd ? mx : mn;
        }
        SORT8(v);

        // S2: full merge of two pair-16s -> sorted-32 over quad
#pragma unroll
        for (int i = 0; i < 8; ++i) t1[i] = __shfl_xor(v[i], 3);
#pragma unroll
        for (int i = 0; i < 8; ++i) {
            u32 mn = umin_(v[i], t1[7 - i]);
            u32 mx = umax_(v[i], t1[7 - i]);
            v[i] = hiP ? mx : mn;
        }
#pragma unroll
        for (int i = 0; i < 8; ++i) t1[i] = __shfl_xor(v[i], 1);
#pragma unroll
        for (int i = 0; i < 8; ++i)
            v[i] = odd ? umax_(v[i], t1[i]) : umin_(v[i], t1[i]);
        SORT8(v);

        // S3 (dist 4) and S4 (dist 8): keep-32 of 64, then clean-32
#pragma unroll
        for (int s = 0; s < 2; ++s) {
            const int mask = s ? 11 : 7;   // flip {quad|octet}, pp, p
#pragma unroll
            for (int i = 0; i < 8; ++i) t1[i] = __shfl_xor(v[i], mask);
#pragma unroll
            for (int i = 0; i < 8; ++i) v[i] = umin_(v[i], t1[7 - i]);   // keep-32
            // clean: j=16 (pp), j=8 (parity), then in-lane
#pragma unroll
            for (int i = 0; i < 8; ++i) t1[i] = __shfl_xor(v[i], 2);
#pragma unroll
            for (int i = 0; i < 8; ++i)
                v[i] = hiP ? umax_(v[i], t1[i]) : umin_(v[i], t1[i]);
#pragma unroll
            for (int i = 0; i < 8; ++i) t1[i] = __shfl_xor(v[i], 1);
#pragma unroll
            for (int i = 0; i < 8; ++i)
                v[i] = odd ? umax_(v[i], t1[i]) : umin_(v[i], t1[i]);
            SORT8(v);
        }

        // output: quad 0 of each group holds sorted top-32; rank = 16*pp+8*p+i
        if ((lane & 12) == 0) {
            const int rank0 = (hiP ? 16 : 0) + (odd ? 8 : 0);
            const int qrow  = n0 + qpair * 32 + h * 16 + 4 * g + r;
            const int obase = (b * N_ + qrow) * 9;
#pragma unroll
            for (int i = 0; i < 8; ++i) {
                const int rank = rank0 + i;
                if (rank < 25 && (rank % 3) == 0)
                    out_src[obase + rank / 3] = (b << 10) | (int)(v[i] & 1023u);
            }
        }
    }

    // ---- dst for this block: 64 queries * 9 = 576 ----
    const int jbase = (b * N_ + n0) * 9;
    for (int idx = tid; idx < 576; idx += 256)
        out_dst[jbase + idx] = (jbase + idx) / 9;
}

// ---------------------------------------------------------------------------
// Fallback (R1 kernel) if workspace is too small for XT+NRM
__global__ __launch_bounds__(256, 2) void knn_kernel(const float* __restrict__ X,
                                                     int* __restrict__ out) {
    __shared__ float smem[16 * N_];
    const int tid = threadIdx.x;
    const int b  = blockIdx.x >> 6;
    const int n0 = (blockIdx.x & 63) * 16;
    const float* __restrict__ xb = X + (size_t)b * C_ * N_;
#pragma unroll
    for (int i = 0; i < 16; ++i) {
        int f = tid + i * 256;
        int c = f >> 4, qq = f & 15;
        smem[f] = xb[c * N_ + n0 + qq];
    }
    __syncthreads();
    float acc[16][4];
#pragma unroll
    for (int q = 0; q < 16; ++q) { acc[q][0] = acc[q][1] = acc[q][2] = acc[q][3] = 0.f; }
    float nrm[4] = {0.f, 0.f, 0.f, 0.f};
    for (int c = 0; c < C_; ++c) {
        const float* __restrict__ xc = xb + c * N_;
        float bv0 = xc[tid], bv1 = xc[tid + 256], bv2 = xc[tid + 512], bv3 = xc[tid + 768];
        const float4* A4 = reinterpret_cast<const float4*>(smem + c * 16);
        float4 a0 = A4[0], a1 = A4[1], a2 = A4[2], a3 = A4[3];
        float aq[16] = {a0.x, a0.y, a0.z, a0.w, a1.x, a1.y, a1.z, a1.w,
                        a2.x, a2.y, a2.z, a2.w, a3.x, a3.y, a3.z, a3.w};
#pragma unroll
        for (int q = 0; q < 16; ++q) {
            acc[q][0] = fmaf(aq[q], bv0, acc[q][0]);
            acc[q][1] = fmaf(aq[q], bv1, acc[q][1]);
            acc[q][2] = fmaf(aq[q], bv2, acc[q][2]);
            acc[q][3] = fmaf(aq[q], bv3, acc[q][3]);
        }
        nrm[0] = fmaf(bv0, bv0, nrm[0]); nrm[1] = fmaf(bv1, bv1, nrm[1]);
        nrm[2] = fmaf(bv2, bv2, nrm[2]); nrm[3] = fmaf(bv3, bv3, nrm[3]);
    }
    __syncthreads();
#pragma unroll
    for (int q = 0; q < 16; ++q) {
        smem[q * N_ + tid]       = nrm[0] - 2.f * acc[q][0];
        smem[q * N_ + tid + 256] = nrm[1] - 2.f * acc[q][1];
        smem[q * N_ + tid + 512] = nrm[2] - 2.f * acc[q][2];
        smem[q * N_ + tid + 768] = nrm[3] - 2.f * acc[q][3];
    }
    __syncthreads();
    const int lane = tid & 63;
    const int w    = tid >> 6;
    int* out_src = out;
    int* out_dst = out + NSRC;
    for (int q = w; q < 16; q += 4) {
        float v[16];
#pragma unroll
        for (int i = 0; i < 16; ++i) v[i] = smem[q * N_ + lane + i * 64];
        float lv = v[0]; int ls = 0;
#pragma unroll
        for (int i = 1; i < 16; ++i) { if (v[i] < lv) { lv = v[i]; ls = i; } }
        int lm = lane + (ls << 6);
        const int obase = (b * N_ + n0 + q) * 9;
#pragma unroll
        for (int r = 0; r < 25; ++r) {
            float bv = lv; int bm = lm;
#pragma unroll
            for (int off = 32; off >= 1; off >>= 1) {
                float ov = __shfl_xor(bv, off);
                int   om = __shfl_xor(bm, off);
                if (ov < bv || (ov == bv && om < bm)) { bv = ov; bm = om; }
            }
            if ((r % 3) == 0 && lane == 0) out_src[obase + r / 3] = b * N_ + bm;
            if (bm == lm) {
#pragma unroll
                for (int i = 0; i < 16; ++i) { if (i == ls) v[i] = 3.4e38f; }
                lv = v[0]; ls = 0;
#pragma unroll
                for (int i = 1; i < 16; ++i) { if (v[i] < lv) { lv = v[i]; ls = i; } }
                lm = lane + (ls << 6);
            }
        }
    }
    const int jbase = (b * N_ + n0) * 9;
    if (tid < 16 * 9) out_dst[jbase + tid] = (jbase + tid) / 9;
}

extern "C" void kernel_launch(void* const* d_in, const int* in_sizes, int n_in,
                              void* d_out, int out_size, void* d_ws, size_t ws_size,
                              hipStream_t stream) {
    (void)in_sizes; (void)n_in; (void)out_size;
    const float* X = (const float*)d_in[0];
    int* out = (int*)d_out;
    const size_t xt_bytes  = (size_t)B_ * N_ * C_ * 2;   // 33,554,432
    const size_t nrm_bytes = (size_t)B_ * N_ * 4;        // 262,144
    if (ws_size >= xt_bytes + nrm_bytes) {
        unsigned short* XT = (unsigned short*)d_ws;
        float* NRM = (float*)((char*)d_ws + xt_bytes);
        trans_kernel<<<dim3(B_ * 16), dim3(256), 0, stream>>>(X, XT, NRM);
        knn_mfma_kernel<<<dim3(B_ * 16), dim3(256), 0, stream>>>(XT, NRM, out);
    } else {
        knn_kernel<<<dim3(B_ * 64), dim3(256), 0, stream>>>(X, out);
    }
}

// Round 5
// 208.908 us; speedup vs baseline: 1.1784x; 1.1784x over previous
//
#include <hip/hip_runtime.h>

// DenseDilatedKnnGraphDGL: B=64, C=256, N=1024, layer_idx=8 -> dilation=3, k=9, k_d=27
// out[0:589824]       = src_d (int32): rank-{0,3,..,24} neighbor index + b*N
// out[589824:1179648] = dst_d (int32): j/9
//
// R12: pair-split sized to fit the 128-VGPR cap at 4 blocks/CU.
//  - R11 spilled because in-loop demand ~136 > 128 ((256,4) cap). R12 trims:
//    keep-4 lists (-8), roffv[8] -> rbase+rot16 recompute (-6), M-copy after
//    the loop (afr dead), odd buffer via ds offset imm (BUFB=17408 < 64K).
//    Demand ~120 <= 128 -> no spill, 4 blocks/CU.
//  - algorithm: 2 A-sets/wave (32 queries), half-point-tile/wave; every
//    ds_read_b128 feeds 2 MFMAs (grid ds_reads 2^20, conflicts 4.19M);
//    partner-wave keep-4 exchange -> bitonic merge -> exact network.
//  - keep-4 margin: merged 4+4 per 64-pt column ~ R8's proven keep-6 regime.

typedef __bf16 bf16x8 __attribute__((ext_vector_type(8)));
typedef float  f32x4  __attribute__((ext_vector_type(4)));
typedef unsigned int u32;

#define B_   64
#define C_   256
#define N_   1024
#define NSRC (B_ * N_ * 9)   // 589824

#define STRIDE_I 1088        // 1024 + 64B pad between staging instructions
#define BUFB     17408       // 16 * STRIDE_I = one 32-row chunk buffer
#define INF_     0xFFFFFFFFu

__device__ __forceinline__ u32 umin_(u32 a, u32 b) { return a < b ? a : b; }
__device__ __forceinline__ u32 umax_(u32 a, u32 b) { return a > b ? a : b; }

__device__ __forceinline__ void load_lds16(const void* g, void* l) {
    __builtin_amdgcn_global_load_lds((const __attribute__((address_space(1))) void*)g,
                                     (__attribute__((address_space(3))) void*)l,
                                     16, 0, 0);
}

// ---------------------------------------------------------------------------
// Kernel 1: transpose + fp32->bf16 + row norms (bf16-consistent), +512 shift.
// grid 1024 = 64 b x 16 n-chunks of 64; block 256.  (unchanged from R1)
__global__ __launch_bounds__(256, 4) void trans_kernel(const float* __restrict__ X,
                                                       unsigned short* __restrict__ XT,
                                                       float* __restrict__ NRM) {
    __shared__ u32 T2[128][68];   // [c-pair][n_local], 34816 B; 68 -> 16B-aligned rows
    const int tid = threadIdx.x;
    const int b   = blockIdx.x >> 4;
    const int n0  = (blockIdx.x & 15) * 64;

    // ---- Phase A ----
    {
        const int cpl = tid >> 4;        // 0..15
        const int s   = tid & 15;        // n quad slot
#pragma unroll
        for (int it = 0; it < 8; ++it) {
            const int c0 = it * 32 + cpl * 2;
            const float* src = X + ((size_t)b * C_ + c0) * N_ + n0 + s * 4;
            float4 f0 = *(const float4*)(src);
            float4 f1 = *(const float4*)(src + N_);
            const float a0[4] = {f0.x, f0.y, f0.z, f0.w};
            const float a1[4] = {f1.x, f1.y, f1.z, f1.w};
            u32 pk[4];
#pragma unroll
            for (int j = 0; j < 4; ++j) {
                u32 u0 = __float_as_uint(a0[j]);
                u32 u1 = __float_as_uint(a1[j]);
                u32 b0 = (u0 + 0x7FFFu + ((u0 >> 16) & 1u)) >> 16;   // RNE
                u32 b1 = (u1 + 0x7FFFu + ((u1 >> 16) & 1u)) >> 16;
                pk[j] = b0 | (b1 << 16);
            }
            *(uint4*)&T2[it * 16 + cpl][s * 4] = make_uint4(pk[0], pk[1], pk[2], pk[3]);
        }
    }
    __syncthreads();

    // ---- Phase B ----
    {
        const int rr = tid >> 2, p = tid & 3;
        unsigned short* xtrow = XT + ((size_t)b * N_ + n0 + rr) * C_;
        float nsq = 0.f;
#pragma unroll
        for (int j = 0; j < 8; ++j) {
            u32 x0 = T2[j * 16 + 4 * p + 0][rr];
            u32 x1 = T2[j * 16 + 4 * p + 1][rr];
            u32 x2 = T2[j * 16 + 4 * p + 2][rr];
            u32 x3 = T2[j * 16 + 4 * p + 3][rr];
            const u32 xs[4] = {x0, x1, x2, x3};
#pragma unroll
            for (int q = 0; q < 4; ++q) {
                float lo = __uint_as_float(xs[q] << 16);
                float hi = __uint_as_float(xs[q] & 0xFFFF0000u);
                nsq = fmaf(lo, lo, fmaf(hi, hi, nsq));
            }
            *(uint4*)((char*)xtrow + j * 64 + p * 16) = make_uint4(x0, x1, x2, x3);
        }
        nsq += __shfl_xor(nsq, 1);
        nsq += __shfl_xor(nsq, 2);
        // +512 shift: f = nrm - 2*dot strictly positive for every query
        // -> float bits directly uint-monotone, no sign-flip transform.
        if (p == 0) NRM[b * N_ + n0 + rr] = nsq + 512.0f;
    }
}

// ---------------------------------------------------------------------------
// bitonic-merge of a bitonic 8-seq in regs -> ascending (phases j=4,2,1)
#define SORT8(v)                                                              \
    do {                                                                      \
        u32 mn, mx;                                                           \
        mn = umin_(v[0], v[4]); mx = umax_(v[0], v[4]); v[0] = mn; v[4] = mx; \
        mn = umin_(v[1], v[5]); mx = umax_(v[1], v[5]); v[1] = mn; v[5] = mx; \
        mn = umin_(v[2], v[6]); mx = umax_(v[2], v[6]); v[2] = mn; v[6] = mx; \
        mn = umin_(v[3], v[7]); mx = umax_(v[3], v[7]); v[3] = mn; v[7] = mx; \
        mn = umin_(v[0], v[2]); mx = umax_(v[0], v[2]); v[0] = mn; v[2] = mx; \
        mn = umin_(v[1], v[3]); mx = umax_(v[1], v[3]); v[1] = mn; v[3] = mx; \
        mn = umin_(v[4], v[6]); mx = umax_(v[4], v[6]); v[4] = mn; v[6] = mx; \
        mn = umin_(v[5], v[7]); mx = umax_(v[5], v[7]); v[5] = mn; v[7] = mx; \
        mn = umin_(v[0], v[1]); mx = umax_(v[0], v[1]); v[0] = mn; v[1] = mx; \
        mn = umin_(v[2], v[3]); mx = umax_(v[2], v[3]); v[2] = mn; v[3] = mx; \
        mn = umin_(v[4], v[5]); mx = umax_(v[4], v[5]); v[4] = mn; v[5] = mx; \
        mn = umin_(v[6], v[7]); mx = umax_(v[6], v[7]); v[6] = mn; v[7] = mx; \
    } while (0)

// Kernel 2: MFMA distances; 2 query-sets/wave, half-point-tile/wave.
// grid 1024 = 64 b x 16 query-chunks of 64; block 256 (4 waves); 4 blocks/CU.
__global__ __launch_bounds__(256, 4) void knn_mfma_kernel(const unsigned short* __restrict__ XT,
                                                          const float* __restrict__ NRM,
                                                          int* __restrict__ out) {
    __shared__ __align__(1024) char Bt[2 * BUFB];   // 34816 B (2 chunk buffers)

    const int tid  = threadIdx.x;
    const int lane = tid & 63;
    const int w    = tid >> 6;
    const int qpair = w >> 1;   // which 32-query group
    const int h     = w & 1;    // which 16-point half of each chunk

    const int bi = blockIdx.x;
    const int b  = (bi & 7) + 8 * (bi >> 7);     // batch-locality swizzle (mod-8)
    const int n0 = ((bi >> 3) & 15) * 64;        // query base (64 queries/block)

    const int lrow = lane & 15;
    const int g    = lane >> 4;
    const bool odd = lane & 1;
    const bool hiP = (lane >> 1) & 1;

    const unsigned short* xtb = XT + (size_t)b * N_ * C_;
    const char* xtc = (const char*)xtb;
    const float* nrmb = NRM + b * N_;

    // A fragments: 2 sets x 8 kc (wave's 32 queries, full K=256) -- 64 VGPRs
    bf16x8 afr0[8], afr1[8];
    {
        const unsigned short* ap0 = xtb + (n0 + qpair * 32 + lrow) * C_ + g * 8;
        const unsigned short* ap1 = ap0 + 16 * C_;
#pragma unroll
        for (int kc = 0; kc < 8; ++kc) afr0[kc] = *(const bf16x8*)(ap0 + kc * 32);
#pragma unroll
        for (int kc = 0; kc < 8; ++kc) afr1[kc] = *(const bf16x8*)(ap1 + kc * 32);
    }

    // per-(qset,row) per-lane sorted top-4 lists (ascending) -- 32 VGPRs
    u32 L0[4][4], L1[4][4];
#pragma unroll
    for (int r = 0; r < 4; ++r)
#pragma unroll
        for (int i = 0; i < 4; ++i) { L0[r][i] = INF_; L1[r][i] = INF_; }

    // LDS read base + rotation (2 VGPRs; per-read addr = rbase + ((kc*64+rot16)&511))
    const u32 rbase = (u32)(h * 8704 + (lrow >> 1) * STRIDE_I + (lrow & 1) * 512);
    const u32 rot16 = (u32)((g + lrow) * 16);

    // staging source voffsets (per-lane, 32-bit); dest is linear per wave
    const int lh   = lane >> 5;
    const int col0 = (lane & 31) * 16;
    u32 voff[4];
#pragma unroll
    for (int i = 0; i < 4; ++i) {
        const int rt  = i * 2 + lh;                           // row within wave's 8
        const int col = (col0 - (((w * 8 + rt) & 15) * 16)) & 511;
        voff[i] = (u32)((w * 8 + rt) * 512 + col);            // chunk 0
    }
    const float* nmp = nrmb + h * 16 + lrow;                  // per-lane norm ptr

    // ---- prologue: stage chunk 0 into buffer 0 ----
#pragma unroll
    for (int i = 0; i < 4; ++i)
        load_lds16(xtc + voff[i], Bt + (w * 4 + i) * STRIDE_I);
#pragma unroll
    for (int i = 0; i < 4; ++i) voff[i] += 16384;             // -> chunk 1
    __syncthreads();

#pragma unroll 1
    for (int cp = 0; cp < 16; ++cp) {
        const int c0v = cp * 2;

        // ================= chunk A: c = c0v (even), reads buf0 =============
        {
            const float nm = nmp[c0v * 32];
            // prefetch c0v+1 into buf1 (always valid: c0v+1 <= 31)
#pragma unroll
            for (int i = 0; i < 4; ++i)
                load_lds16(xtc + voff[i], Bt + BUFB + (w * 4 + i) * STRIDE_I);
#pragma unroll
            for (int i = 0; i < 4; ++i) voff[i] += 16384;

            f32x4 acc0 = {0.f, 0.f, 0.f, 0.f};
            f32x4 acc1 = {0.f, 0.f, 0.f, 0.f};
#pragma unroll
            for (int kc = 0; kc < 8; ++kc) {
                const u32 mc = (u32)((kc * 64 + rot16) & 511);
                bf16x8 bfr = *(const bf16x8*)(Bt + rbase + mc);
                acc0 = __builtin_amdgcn_mfma_f32_16x16x32_bf16(afr0[kc], bfr, acc0, 0, 0, 0);
                acc1 = __builtin_amdgcn_mfma_f32_16x16x32_bf16(afr1[kc], bfr, acc1, 0, 0, 0);
            }
            const u32 m = (u32)(c0v * 32 + h * 16 + lrow);
#pragma unroll
            for (int r = 0; r < 4; ++r) {
                float f = fmaf(-2.f, acc0[r], nm);            // > 0 (NRM has +512)
                u32 cur = (__float_as_uint(f) & 0xFFFFFC00u) | m;
                u32 p0 = L0[r][0], p1 = L0[r][1], p2 = L0[r][2], p3 = L0[r][3];
                L0[r][0] = umin_(p0, cur);
                L0[r][1] = umax_(p0, umin_(p1, cur));
                L0[r][2] = umax_(p1, umin_(p2, cur));
                L0[r][3] = umax_(p2, umin_(p3, cur));
            }
#pragma unroll
            for (int r = 0; r < 4; ++r) {
                float f = fmaf(-2.f, acc1[r], nm);
                u32 cur = (__float_as_uint(f) & 0xFFFFFC00u) | m;
                u32 p0 = L1[r][0], p1 = L1[r][1], p2 = L1[r][2], p3 = L1[r][3];
                L1[r][0] = umin_(p0, cur);
                L1[r][1] = umax_(p0, umin_(p1, cur));
                L1[r][2] = umax_(p1, umin_(p2, cur));
                L1[r][3] = umax_(p2, umin_(p3, cur));
            }
            __syncthreads();   // publishes buf1, releases buf0
        }

        // ================= chunk B: c = c0v+1 (odd), reads buf1 ============
        {
            const float nm = nmp[c0v * 32 + 32];
            if (cp < 15) {     // prefetch c0v+2 into buf0
#pragma unroll
                for (int i = 0; i < 4; ++i)
                    load_lds16(xtc + voff[i], Bt + (w * 4 + i) * STRIDE_I);
#pragma unroll
                for (int i = 0; i < 4; ++i) voff[i] += 16384;
            }

            f32x4 acc0 = {0.f, 0.f, 0.f, 0.f};
            f32x4 acc1 = {0.f, 0.f, 0.f, 0.f};
#pragma unroll
            for (int kc = 0; kc < 8; ++kc) {
                const u32 mc = (u32)((kc * 64 + rot16) & 511);
                bf16x8 bfr = *(const bf16x8*)(Bt + BUFB + rbase + mc);
                acc0 = __builtin_amdgcn_mfma_f32_16x16x32_bf16(afr0[kc], bfr, acc0, 0, 0, 0);
                acc1 = __builtin_amdgcn_mfma_f32_16x16x32_bf16(afr1[kc], bfr, acc1, 0, 0, 0);
            }
            const u32 m = (u32)(c0v * 32 + 32 + h * 16 + lrow);
#pragma unroll
            for (int r = 0; r < 4; ++r) {
                float f = fmaf(-2.f, acc0[r], nm);
                u32 cur = (__float_as_uint(f) & 0xFFFFFC00u) | m;
                u32 p0 = L0[r][0], p1 = L0[r][1], p2 = L0[r][2], p3 = L0[r][3];
                L0[r][0] = umin_(p0, cur);
                L0[r][1] = umax_(p0, umin_(p1, cur));
                L0[r][2] = umax_(p1, umin_(p2, cur));
                L0[r][3] = umax_(p2, umin_(p3, cur));
            }
#pragma unroll
            for (int r = 0; r < 4; ++r) {
                float f = fmaf(-2.f, acc1[r], nm);
                u32 cur = (__float_as_uint(f) & 0xFFFFFC00u) | m;
                u32 p0 = L1[r][0], p1 = L1[r][1], p2 = L1[r][2], p3 = L1[r][3];
                L1[r][0] = umin_(p0, cur);
                L1[r][1] = umax_(p0, umin_(p1, cur));
                L1[r][2] = umax_(p1, umin_(p2, cur));
                L1[r][3] = umax_(p2, umin_(p3, cur));
            }
            __syncthreads();   // publishes buf0 (next A), releases buf1
        }
    }

    // ---- exchange: partner waves (w^1) cover the other point half ----
    // (afr dead here -> register pressure is irrelevant in the epilogue)
    u32 M[4][4];
#pragma unroll
    for (int r = 0; r < 4; ++r)
#pragma unroll
        for (int j = 0; j < 4; ++j) M[r][j] = h ? L1[r][j] : L0[r][j];

    {
        const u32 mybase = (u32)((w * 64 + lane) * 64);   // 16 u32 per lane
        if (h == 0) {
#pragma unroll
            for (int j = 0; j < 4; ++j)
                *(uint4*)(Bt + mybase + j * 16) =
                    make_uint4(L1[0][j], L1[1][j], L1[2][j], L1[3][j]);
        } else {
#pragma unroll
            for (int j = 0; j < 4; ++j)
                *(uint4*)(Bt + mybase + j * 16) =
                    make_uint4(L0[0][j], L0[1][j], L0[2][j], L0[3][j]);
        }
    }
    __syncthreads();
    u32 P[4][4];
    {
        const u32 exbase = (u32)(((w ^ 1) * 64 + lane) * 64);
#pragma unroll
        for (int j = 0; j < 4; ++j) {
            uint4 q = *(const uint4*)(Bt + exbase + j * 16);
            P[0][j] = q.x; P[1][j] = q.y; P[2][j] = q.z; P[3][j] = q.w;
        }
    }

    // ---- selection: exact distributed top-32 per query row (row = 4g+r) ----
    int* out_src = out;
    int* out_dst = out + NSRC;
#pragma unroll
    for (int r = 0; r < 4; ++r) {
        u32 v[8], t1[8];
        // own asc-4 ++ partner desc-4 = bitonic-8 -> SORT8 = sorted top-8/lane
        v[0] = M[r][0]; v[1] = M[r][1]; v[2] = M[r][2]; v[3] = M[r][3];
        v[4] = P[r][3]; v[5] = P[r][2]; v[6] = P[r][1]; v[7] = P[r][0];
        SORT8(v);

        // S1: pair merge, keep all 16 (e: ranks 0-7, o: 8-15)
#pragma unroll
        for (int i = 0; i < 8; ++i) t1[i] = __shfl_xor(v[i], 1);
#pragma unroll
        for (int i = 0; i < 8; ++i) {
            u32 mn = umin_(v[i], t1[7 - i]);
            u32 mx = umax_(v[i], t1[7 - i]);
            v[i] = odd ? mx : mn;
        }
        SORT8(v);

        // S2: full merge of two pair-16s -> sorted-32 over quad
#pragma unroll
        for (int i = 0; i < 8; ++i) t1[i] = __shfl_xor(v[i], 3);
#pragma unroll
        for (int i = 0; i < 8; ++i) {
            u32 mn = umin_(v[i], t1[7 - i]);
            u32 mx = umax_(v[i], t1[7 - i]);
            v[i] = hiP ? mx : mn;
        }
#pragma unroll
        for (int i = 0; i < 8; ++i) t1[i] = __shfl_xor(v[i], 1);
#pragma unroll
        for (int i = 0; i < 8; ++i)
            v[i] = odd ? umax_(v[i], t1[i]) : umin_(v[i], t1[i]);
        SORT8(v);

        // S3 (dist 4) and S4 (dist 8): keep-32 of 64, then clean-32
#pragma unroll
        for (int s = 0; s < 2; ++s) {
            const int mask = s ? 11 : 7;   // flip {quad|octet}, pp, p
#pragma unroll
            for (int i = 0; i < 8; ++i) t1[i] = __shfl_xor(v[i], mask);
#pragma unroll
            for (int i = 0; i < 8; ++i) v[i] = umin_(v[i], t1[7 - i]);   // keep-32
            // clean: j=16 (pp), j=8 (parity), then in-lane
#pragma unroll
            for (int i = 0; i < 8; ++i) t1[i] = __shfl_xor(v[i], 2);
#pragma unroll
            for (int i = 0; i < 8; ++i)
                v[i] = hiP ? umax_(v[i], t1[i]) : umin_(v[i], t1[i]);
#pragma unroll
            for (int i = 0; i < 8; ++i) t1[i] = __shfl_xor(v[i], 1);
#pragma unroll
            for (int i = 0; i < 8; ++i)
                v[i] = odd ? umax_(v[i], t1[i]) : umin_(v[i], t1[i]);
            SORT8(v);
        }

        // output: quad 0 of each group holds sorted top-32; rank = 16*pp+8*p+i
        if ((lane & 12) == 0) {
            const int rank0 = (hiP ? 16 : 0) + (odd ? 8 : 0);
            const int qrow  = n0 + qpair * 32 + h * 16 + 4 * g + r;
            const int obase = (b * N_ + qrow) * 9;
#pragma unroll
            for (int i = 0; i < 8; ++i) {
                const int rank = rank0 + i;
                if (rank < 25 && (rank % 3) == 0)
                    out_src[obase + rank / 3] = (b << 10) | (int)(v[i] & 1023u);
            }
        }
    }

    // ---- dst for this block: 64 queries * 9 = 576 ----
    const int jbase = (b * N_ + n0) * 9;
    for (int idx = tid; idx < 576; idx += 256)
        out_dst[jbase + idx] = (jbase + idx) / 9;
}

// ---------------------------------------------------------------------------
// Fallback (R1 kernel) if workspace is too small for XT+NRM
__global__ __launch_bounds__(256, 2) void knn_kernel(const float* __restrict__ X,
                                                     int* __restrict__ out) {
    __shared__ float smem[16 * N_];
    const int tid = threadIdx.x;
    const int b  = blockIdx.x >> 6;
    const int n0 = (blockIdx.x & 63) * 16;
    const float* __restrict__ xb = X + (size_t)b * C_ * N_;
#pragma unroll
    for (int i = 0; i < 16; ++i) {
        int f = tid + i * 256;
        int c = f >> 4, qq = f & 15;
        smem[f] = xb[c * N_ + n0 + qq];
    }
    __syncthreads();
    float acc[16][4];
#pragma unroll
    for (int q = 0; q < 16; ++q) { acc[q][0] = acc[q][1] = acc[q][2] = acc[q][3] = 0.f; }
    float nrm[4] = {0.f, 0.f, 0.f, 0.f};
    for (int c = 0; c < C_; ++c) {
        const float* __restrict__ xc = xb + c * N_;
        float bv0 = xc[tid], bv1 = xc[tid + 256], bv2 = xc[tid + 512], bv3 = xc[tid + 768];
        const float4* A4 = reinterpret_cast<const float4*>(smem + c * 16);
        float4 a0 = A4[0], a1 = A4[1], a2 = A4[2], a3 = A4[3];
        float aq[16] = {a0.x, a0.y, a0.z, a0.w, a1.x, a1.y, a1.z, a1.w,
                        a2.x, a2.y, a2.z, a2.w, a3.x, a3.y, a3.z, a3.w};
#pragma unroll
        for (int q = 0; q < 16; ++q) {
            acc[q][0] = fmaf(aq[q], bv0, acc[q][0]);
            acc[q][1] = fmaf(aq[q], bv1, acc[q][1]);
            acc[q][2] = fmaf(aq[q], bv2, acc[q][2]);
            acc[q][3] = fmaf(aq[q], bv3, acc[q][3]);
        }
        nrm[0] = fmaf(bv0, bv0, nrm[0]); nrm[1] = fmaf(bv1, bv1, nrm[1]);
        nrm[2] = fmaf(bv2, bv2, nrm[2]); nrm[3] = fmaf(bv3, bv3, nrm[3]);
    }
    __syncthreads();
#pragma unroll
    for (int q = 0; q < 16; ++q) {
        smem[q * N_ + tid]       = nrm[0] - 2.f * acc[q][0];
        smem[q * N_ + tid + 256] = nrm[1] - 2.f * acc[q][1];
        smem[q * N_ + tid + 512] = nrm[2] - 2.f * acc[q][2];
        smem[q * N_ + tid + 768] = nrm[3] - 2.f * acc[q][3];
    }
    __syncthreads();
    const int lane = tid & 63;
    const int w    = tid >> 6;
    int* out_src = out;
    int* out_dst = out + NSRC;
    for (int q = w; q < 16; q += 4) {
        float v[16];
#pragma unroll
        for (int i = 0; i < 16; ++i) v[i] = smem[q * N_ + lane + i * 64];
        float lv = v[0]; int ls = 0;
#pragma unroll
        for (int i = 1; i < 16; ++i) { if (v[i] < lv) { lv = v[i]; ls = i; } }
        int lm = lane + (ls << 6);
        const int obase = (b * N_ + n0 + q) * 9;
#pragma unroll
        for (int r = 0; r < 25; ++r) {
            float bv = lv; int bm = lm;
#pragma unroll
            for (int off = 32; off >= 1; off >>= 1) {
                float ov = __shfl_xor(bv, off);
                int   om = __shfl_xor(bm, off);
                if (ov < bv || (ov == bv && om < bm)) { bv = ov; bm = om; }
            }
            if ((r % 3) == 0 && lane == 0) out_src[obase + r / 3] = b * N_ + bm;
            if (bm == lm) {
#pragma unroll
                for (int i = 0; i < 16; ++i) { if (i == ls) v[i] = 3.4e38f; }
                lv = v[0]; ls = 0;
#pragma unroll
                for (int i = 1; i < 16; ++i) { if (v[i] < lv) { lv = v[i]; ls = i; } }
                lm = lane + (ls << 6);
            }
        }
    }
    const int jbase = (b * N_ + n0) * 9;
    if (tid < 16 * 9) out_dst[jbase + tid] = (jbase + tid) / 9;
}

extern "C" void kernel_launch(void* const* d_in, const int* in_sizes, int n_in,
                              void* d_out, int out_size, void* d_ws, size_t ws_size,
                              hipStream_t stream) {
    (void)in_sizes; (void)n_in; (void)out_size;
    const float* X = (const float*)d_in[0];
    int* out = (int*)d_out;
    const size_t xt_bytes  = (size_t)B_ * N_ * C_ * 2;   // 33,554,432
    const size_t nrm_bytes = (size_t)B_ * N_ * 4;        // 262,144
    if (ws_size >= xt_bytes + nrm_bytes) {
        unsigned short* XT = (unsigned short*)d_ws;
        float* NRM = (float*)((char*)d_ws + xt_bytes);
        trans_kernel<<<dim3(B_ * 16), dim3(256), 0, stream>>>(X, XT, NRM);
        knn_mfma_kernel<<<dim3(B_ * 16), dim3(256), 0, stream>>>(XT, NRM, out);
    } else {
        knn_kernel<<<dim3(B_ * 64), dim3(256), 0, stream>>>(X, out);
    }
}

// Round 6
// 169.888 us; speedup vs baseline: 1.4490x; 1.2297x over previous
//
#include <hip/hip_runtime.h>

// DenseDilatedKnnGraphDGL: B=64, C=256, N=1024, layer_idx=8 -> dilation=3, k=9, k_d=27
// out[0:589824]       = src_d (int32): rank-{0,3,..,24} neighbor index + b*N
// out[589824:1179648] = dst_d (int32): j/9
//
// R13: knn reverted to the proven R8 kernel (82us, VGPR 56, no spill); the
// pair-split experiments (R9-R12) are abandoned (3x scratch-spill, condemned).
// NEW TARGET: trans_kernel was ~85us (= total - knn across R0/R1/R4/R5), 5x its
// ~16us BW floor, due to 256B strided reads + 64B scattered writes.
//  - new tiling: block = (b, 64-c block, 256-n block), grid 1024, 4/CU.
//    Phase A reads FULL 1KB contiguous rows (64 lanes x float4); Phase B
//    writes XT in 128B contiguous segments (8 lanes x uint4 per n-row).
//  - norms: per-block 64-channel partials (8 fma + 3 shfl per n), summed
//    across the 4 c-blocks via DETERMINISTIC fixed-point u32 atomicAdd
//    (scale 2^20), NRM zeroed by hipMemsetAsync (stream-ordered).
//  - knn: nm = (float)nrmu[m] * 2^-20 + 512 (norm delta ~1e-4 << 0.0625 key
//    granularity of the 10-bit-truncated sort key -> ranking unchanged).

typedef __bf16 bf16x8 __attribute__((ext_vector_type(8)));
typedef float  f32x4  __attribute__((ext_vector_type(4)));
typedef unsigned int u32;

#define B_   64
#define C_   256
#define N_   1024
#define NSRC (B_ * N_ * 9)   // 589824

#define STRIDE_I 1088        // 1024 + 64B pad between staging instructions
#define REGION_W 8704        // 8 * STRIDE_I per wave-region (16 rows)

__device__ __forceinline__ u32 umin_(u32 a, u32 b) { return a < b ? a : b; }
__device__ __forceinline__ u32 umax_(u32 a, u32 b) { return a > b ? a : b; }

__device__ __forceinline__ void load_lds16(const void* g, void* l) {
    __builtin_amdgcn_global_load_lds((const __attribute__((address_space(1))) void*)g,
                                     (__attribute__((address_space(3))) void*)l,
                                     16, 0, 0);
}

// ---------------------------------------------------------------------------
// Kernel 1: transpose + fp32->bf16 + partial row norms (bf16-consistent).
// grid 1024 = 64 b x 4 c-blocks(64) x 4 n-blocks(256); block 256.
// Phase A: wave w, iter i: row-pair rp=i*4+w; lane l reads float4 at
//   X[b][c0+2rp][n0+4l] and +N_ -> two 1KB fully-coalesced row reads; packs
//   (bf16 even c | bf16 odd c << 16) -> 4 x ds_write_b32 to T2[rp][4l+j].
// Phase B: thread (k=tid&7, nB=tid>>3): for 8 n: 4 x ds_read_b32 T2[4k+q][n]
//   (banks (rp+n)%32, conflict-free) -> uint4 write to XT[n][c0+8k..] (8
//   lanes = 128B contiguous); 8 bf16^2 fma partial norm, shfl-reduce over k,
//   fixed-point u32 atomicAdd into NRMU (deterministic).
__global__ __launch_bounds__(256, 4) void trans_kernel(const float* __restrict__ X,
                                                       unsigned short* __restrict__ XT,
                                                       u32* __restrict__ NRMU) {
    __shared__ u32 T2[32][257];   // [c-pair][n_local], 32896 B
    const int tid = threadIdx.x;
    const int bi  = blockIdx.x;
    const int b   = bi >> 4;
    const int c0  = ((bi >> 2) & 3) * 64;
    const int n0  = (bi & 3) * 256;
    const int w   = tid >> 6;
    const int l   = tid & 63;

    // ---- Phase A: 1KB-coalesced row reads ----
    {
        const int n4 = l * 4;
#pragma unroll
        for (int i = 0; i < 8; ++i) {
            const int rp = i * 4 + w;
            const float* src = X + ((size_t)(b * C_ + c0 + 2 * rp)) * N_ + n0 + n4;
            float4 f0 = *(const float4*)(src);
            float4 f1 = *(const float4*)(src + N_);
            const float a0[4] = {f0.x, f0.y, f0.z, f0.w};
            const float a1[4] = {f1.x, f1.y, f1.z, f1.w};
#pragma unroll
            for (int j = 0; j < 4; ++j) {
                u32 u0 = __float_as_uint(a0[j]);
                u32 u1 = __float_as_uint(a1[j]);
                u32 b0 = (u0 + 0x7FFFu + ((u0 >> 16) & 1u)) >> 16;   // RNE
                u32 b1 = (u1 + 0x7FFFu + ((u1 >> 16) & 1u)) >> 16;
                T2[rp][n4 + j] = b0 | (b1 << 16);
            }
        }
    }
    __syncthreads();

    // ---- Phase B: 128B-coalesced XT writes + partial norms ----
    {
        const int k  = tid & 7;    // c-octet slot (8 bf16 = 16B)
        const int nB = tid >> 3;   // n owner within 32-group
#pragma unroll
        for (int nn = 0; nn < 8; ++nn) {
            const int n = nn * 32 + nB;
            u32 x0 = T2[4 * k + 0][n];
            u32 x1 = T2[4 * k + 1][n];
            u32 x2 = T2[4 * k + 2][n];
            u32 x3 = T2[4 * k + 3][n];
            const u32 xs[4] = {x0, x1, x2, x3};
            float ps = 0.f;
#pragma unroll
            for (int q = 0; q < 4; ++q) {
                float lo = __uint_as_float(xs[q] << 16);
                float hi = __uint_as_float(xs[q] & 0xFFFF0000u);
                ps = fmaf(lo, lo, fmaf(hi, hi, ps));
            }
            *(uint4*)((char*)XT + ((size_t)(b * N_ + n0 + n)) * 512 + c0 * 2 + k * 16) =
                make_uint4(x0, x1, x2, x3);
            // reduce over the 8 k-lanes (consecutive tids -> same wave)
            ps += __shfl_xor(ps, 1);
            ps += __shfl_xor(ps, 2);
            ps += __shfl_xor(ps, 4);
            if (k == 0)
                atomicAdd(NRMU + b * N_ + n0 + n, (u32)(ps * 1048576.0f + 0.5f));
        }
    }
}

// ---------------------------------------------------------------------------
// bitonic-merge of a bitonic 8-seq in regs -> ascending (phases j=4,2,1)
#define SORT8(v)                                                              \
    do {                                                                      \
        u32 mn, mx;                                                           \
        mn = umin_(v[0], v[4]); mx = umax_(v[0], v[4]); v[0] = mn; v[4] = mx; \
        mn = umin_(v[1], v[5]); mx = umax_(v[1], v[5]); v[1] = mn; v[5] = mx; \
        mn = umin_(v[2], v[6]); mx = umax_(v[2], v[6]); v[2] = mn; v[6] = mx; \
        mn = umin_(v[3], v[7]); mx = umax_(v[3], v[7]); v[3] = mn; v[7] = mx; \
        mn = umin_(v[0], v[2]); mx = umax_(v[0], v[2]); v[0] = mn; v[2] = mx; \
        mn = umin_(v[1], v[3]); mx = umax_(v[1], v[3]); v[1] = mn; v[3] = mx; \
        mn = umin_(v[4], v[6]); mx = umax_(v[4], v[6]); v[4] = mn; v[6] = mx; \
        mn = umin_(v[5], v[7]); mx = umax_(v[5], v[7]); v[5] = mn; v[7] = mx; \
        mn = umin_(v[0], v[1]); mx = umax_(v[0], v[1]); v[0] = mn; v[1] = mx; \
        mn = umin_(v[2], v[3]); mx = umax_(v[2], v[3]); v[2] = mn; v[3] = mx; \
        mn = umin_(v[4], v[5]); mx = umax_(v[4], v[5]); v[4] = mn; v[5] = mx; \
        mn = umin_(v[6], v[7]); mx = umax_(v[6], v[7]); v[6] = mn; v[7] = mx; \
    } while (0)

// Kernel 2: MFMA distances (shared LDS staging) + exact distributed top-32.
// grid 1024 = 64 b x 16 query-chunks of 64; block 256 (4 waves); 4 blocks/CU.
// (R8 structure verbatim; only the norm load changed to fixed-point u32.)
__global__ __launch_bounds__(256, 4) void knn_mfma_kernel(const unsigned short* __restrict__ XT,
                                                          const u32* __restrict__ NRMU,
                                                          int* __restrict__ out) {
    __shared__ __align__(1024) char Bt[2 * 17408];   // 34816 B (2 chunk buffers)

    const int tid  = threadIdx.x;
    const int lane = tid & 63;
    const int w    = tid >> 6;

    const int bi = blockIdx.x;
    const int b  = (bi & 7) + 8 * (bi >> 7);     // batch-locality swizzle (mod-8)
    const int n0 = ((bi >> 3) & 15) * 64;        // query base (64 queries/block)

    const int lrow = lane & 15;
    const int g    = lane >> 4;
    const bool odd = lane & 1;
    const bool hiP = (lane >> 1) & 1;

    const unsigned short* xtb = XT + (size_t)b * N_ * C_;
    const u32* nrmb = NRMU + b * N_;

    // A fragments: wave w's 16 queries (rows n0 + w*16 + lrow), full K=256
    bf16x8 afr[8];
    {
        const unsigned short* ap = xtb + (n0 + w * 16 + lrow) * C_ + g * 8;
#pragma unroll
        for (int kc = 0; kc < 8; ++kc)
            afr[kc] = *(const bf16x8*)(ap + kc * 32);
    }

    // per-round per-lane sorted top-6 lists (ascending)
    u32 L[4][6];
#pragma unroll
    for (int r = 0; r < 4; ++r)
#pragma unroll
        for (int i = 0; i < 6; ++i) L[r][i] = 0xFFFFFFFFu;

    const int lh   = lane >> 5;
    const int col0 = (lane & 31) * 16;

    // ---- prologue: stage chunk 0 (rows 0..31) into buffer 0 ----
    {
        const char* gb = (const char*)(xtb + (size_t)(w * 8) * C_);
        char* ldsw = Bt + (w * 4) * STRIDE_I;
#pragma unroll
        for (int i = 0; i < 4; ++i) {
            const int rt  = i * 2 + lh;                       // 0..7 within wave's 8 rows
            const int col = (col0 - (((w * 8 + rt) & 15) * 16)) & 511;
            load_lds16(gb + (size_t)rt * 512 + col, ldsw + i * STRIDE_I);
        }
    }
    __syncthreads();

#pragma unroll 1
    for (int c = 0; c < 32; ++c) {
        // nrm for this chunk (u32 fixed-point), issued BEFORE the stage loads
        const u32 nu0 = nrmb[c * 32 + lrow];
        const u32 nu1 = nrmb[c * 32 + 16 + lrow];
        const float nm0 = fmaf((float)nu0, 0x1p-20f, 512.0f);
        const float nm1 = fmaf((float)nu1, 0x1p-20f, 512.0f);

        // ---- stage chunk c+1 into the other buffer (hides under compute) ----
        if (c < 31) {
            const int cn = c + 1;
            const char* gb = (const char*)(xtb + (size_t)(cn * 32 + w * 8) * C_);
            char* ldsw = Bt + (cn & 1) * 17408 + (w * 4) * STRIDE_I;
#pragma unroll
            for (int i = 0; i < 4; ++i) {
                const int rt  = i * 2 + lh;
                const int col = (col0 - (((w * 8 + rt) & 15) * 16)) & 511;
                load_lds16(gb + (size_t)rt * 512 + col, ldsw + i * STRIDE_I);
            }
        }

        // ---- compute: 2 tiles (16 queries x 32 points) from buf[c&1] ----
        const char* bufc = Bt + (c & 1) * 17408;
#pragma unroll
        for (int t = 0; t < 2; ++t) {
            const char* rbase = bufc + t * 8704 + (lrow >> 1) * STRIDE_I + (lrow & 1) * 512;
            f32x4 acc = {0.f, 0.f, 0.f, 0.f};
#pragma unroll
            for (int kc = 0; kc < 8; ++kc) {
                bf16x8 bfr = *(const bf16x8*)(rbase + ((kc * 64 + g * 16 + lrow * 16) & 511));
                acc = __builtin_amdgcn_mfma_f32_16x16x32_bf16(afr[kc], bfr, acc, 0, 0, 0);
            }
            const int m = c * 32 + t * 16 + lrow;
            const float nm = t ? nm1 : nm0;
#pragma unroll
            for (int r = 0; r < 4; ++r) {
                float f = fmaf(-2.f, acc[r], nm);              // > 0 (norm carries +512)
                u32 u = __float_as_uint(f);                    // uint-monotone directly
                u32 cur = (u & 0xFFFFFC00u) | (u32)m;          // index in low 10 bits
                // parallel sorted-insert: new_ai = max(a[i-1], min(a[i], cur))
                u32 p0 = L[r][0], p1 = L[r][1], p2 = L[r][2];
                u32 p3 = L[r][3], p4 = L[r][4], p5 = L[r][5];
                L[r][0] = umin_(p0, cur);
                L[r][1] = umax_(p0, umin_(p1, cur));
                L[r][2] = umax_(p1, umin_(p2, cur));
                L[r][3] = umax_(p2, umin_(p3, cur));
                L[r][4] = umax_(p3, umin_(p4, cur));
                L[r][5] = umax_(p4, umin_(p5, cur));
            }
        }
        // implicit vmcnt(0) here = pipeline drain for stage(c+1); also
        // publishes buf[(c+1)&1] and releases buf[c&1] for stage(c+2)
        __syncthreads();
    }

    // ---- selection: exact distributed top-32 per query row (row = 4g+r) ----
    int* out_src = out;
    int* out_dst = out + NSRC;
#pragma unroll
    for (int r = 0; r < 4; ++r) {
        u32 v[8], t1[8];
#pragma unroll
        for (int i = 0; i < 6; ++i) v[i] = L[r][i];
        v[6] = 0xFFFFFFFFu; v[7] = 0xFFFFFFFFu;

        // S1: pair merge, keep all 16 (e: ranks 0-7, o: 8-15)
#pragma unroll
        for (int i = 0; i < 8; ++i) t1[i] = __shfl_xor(v[i], 1);
#pragma unroll
        for (int i = 0; i < 8; ++i) {
            u32 mn = umin_(v[i], t1[7 - i]);
            u32 mx = umax_(v[i], t1[7 - i]);
            v[i] = odd ? mx : mn;
        }
        SORT8(v);

        // S2: full merge of two pair-16s -> sorted-32 over quad
#pragma unroll
        for (int i = 0; i < 8; ++i) t1[i] = __shfl_xor(v[i], 3);
#pragma unroll
        for (int i = 0; i < 8; ++i) {
            u32 mn = umin_(v[i], t1[7 - i]);
            u32 mx = umax_(v[i], t1[7 - i]);
            v[i] = hiP ? mx : mn;
        }
#pragma unroll
        for (int i = 0; i < 8; ++i) t1[i] = __shfl_xor(v[i], 1);
#pragma unroll
        for (int i = 0; i < 8; ++i)
            v[i] = odd ? umax_(v[i], t1[i]) : umin_(v[i], t1[i]);
        SORT8(v);

        // S3 (dist 4) and S4 (dist 8): keep-32 of 64, then clean-32
#pragma unroll
        for (int s = 0; s < 2; ++s) {
            const int mask = s ? 11 : 7;   // flip {quad|octet}, pp, p
#pragma unroll
            for (int i = 0; i < 8; ++i) t1[i] = __shfl_xor(v[i], mask);
#pragma unroll
            for (int i = 0; i < 8; ++i) v[i] = umin_(v[i], t1[7 - i]);   // keep-32
            // clean: j=16 (pp), j=8 (parity), then in-lane
#pragma unroll
            for (int i = 0; i < 8; ++i) t1[i] = __shfl_xor(v[i], 2);
#pragma unroll
            for (int i = 0; i < 8; ++i)
                v[i] = hiP ? umax_(v[i], t1[i]) : umin_(v[i], t1[i]);
#pragma unroll
            for (int i = 0; i < 8; ++i) t1[i] = __shfl_xor(v[i], 1);
#pragma unroll
            for (int i = 0; i < 8; ++i)
                v[i] = odd ? umax_(v[i], t1[i]) : umin_(v[i], t1[i]);
            SORT8(v);
        }

        // output: quad 0 of each group holds sorted top-32; rank = 16*pp+8*p+i
        if ((lane & 12) == 0) {
            const int rank0 = (hiP ? 16 : 0) + (odd ? 8 : 0);
            const int obase = (b * N_ + n0 + w * 16 + 4 * g + r) * 9;
#pragma unroll
            for (int i = 0; i < 8; ++i) {
                const int rank = rank0 + i;
                if (rank < 25 && (rank % 3) == 0)
                    out_src[obase + rank / 3] = (b << 10) | (int)(v[i] & 1023u);
            }
        }
    }

    // ---- dst for this block: 64 queries * 9 = 576 ----
    const int jbase = (b * N_ + n0) * 9;
    for (int idx = tid; idx < 576; idx += 256)
        out_dst[jbase + idx] = (jbase + idx) / 9;
}

// ---------------------------------------------------------------------------
// Fallback (R1 kernel) if workspace is too small for XT+NRM
__global__ __launch_bounds__(256, 2) void knn_kernel(const float* __restrict__ X,
                                                     int* __restrict__ out) {
    __shared__ float smem[16 * N_];
    const int tid = threadIdx.x;
    const int b  = blockIdx.x >> 6;
    const int n0 = (blockIdx.x & 63) * 16;
    const float* __restrict__ xb = X + (size_t)b * C_ * N_;
#pragma unroll
    for (int i = 0; i < 16; ++i) {
        int f = tid + i * 256;
        int c = f >> 4, qq = f & 15;
        smem[f] = xb[c * N_ + n0 + qq];
    }
    __syncthreads();
    float acc[16][4];
#pragma unroll
    for (int q = 0; q < 16; ++q) { acc[q][0] = acc[q][1] = acc[q][2] = acc[q][3] = 0.f; }
    float nrm[4] = {0.f, 0.f, 0.f, 0.f};
    for (int c = 0; c < C_; ++c) {
        const float* __restrict__ xc = xb + c * N_;
        float bv0 = xc[tid], bv1 = xc[tid + 256], bv2 = xc[tid + 512], bv3 = xc[tid + 768];
        const float4* A4 = reinterpret_cast<const float4*>(smem + c * 16);
        float4 a0 = A4[0], a1 = A4[1], a2 = A4[2], a3 = A4[3];
        float aq[16] = {a0.x, a0.y, a0.z, a0.w, a1.x, a1.y, a1.z, a1.w,
                        a2.x, a2.y, a2.z, a2.w, a3.x, a3.y, a3.z, a3.w};
#pragma unroll
        for (int q = 0; q < 16; ++q) {
            acc[q][0] = fmaf(aq[q], bv0, acc[q][0]);
            acc[q][1] = fmaf(aq[q], bv1, acc[q][1]);
            acc[q][2] = fmaf(aq[q], bv2, acc[q][2]);
            acc[q][3] = fmaf(aq[q], bv3, acc[q][3]);
        }
        nrm[0] = fmaf(bv0, bv0, nrm[0]); nrm[1] = fmaf(bv1, bv1, nrm[1]);
        nrm[2] = fmaf(bv2, bv2, nrm[2]); nrm[3] = fmaf(bv3, bv3, nrm[3]);
    }
    __syncthreads();
#pragma unroll
    for (int q = 0; q < 16; ++q) {
        smem[q * N_ + tid]       = nrm[0] - 2.f * acc[q][0];
        smem[q * N_ + tid + 256] = nrm[1] - 2.f * acc[q][1];
        smem[q * N_ + tid + 512] = nrm[2] - 2.f * acc[q][2];
        smem[q * N_ + tid + 768] = nrm[3] - 2.f * acc[q][3];
    }
    __syncthreads();
    const int lane = tid & 63;
    const int w    = tid >> 6;
    int* out_src = out;
    int* out_dst = out + NSRC;
    for (int q = w; q < 16; q += 4) {
        float v[16];
#pragma unroll
        for (int i = 0; i < 16; ++i) v[i] = smem[q * N_ + lane + i * 64];
        float lv = v[0]; int ls = 0;
#pragma unroll
        for (int i = 1; i < 16; ++i) { if (v[i] < lv) { lv = v[i]; ls = i; } }
        int lm = lane + (ls << 6);
        const int obase = (b * N_ + n0 + q) * 9;
#pragma unroll
        for (int r = 0; r < 25; ++r) {
            float bv = lv; int bm = lm;
#pragma unroll
            for (int off = 32; off >= 1; off >>= 1) {
                float ov = __shfl_xor(bv, off);
                int   om = __shfl_xor(bm, off);
                if (ov < bv || (ov == bv && om < bm)) { bv = ov; bm = om; }
            }
            if ((r % 3) == 0 && lane == 0) out_src[obase + r / 3] = b * N_ + bm;
            if (bm == lm) {
#pragma unroll
                for (int i = 0; i < 16; ++i) { if (i == ls) v[i] = 3.4e38f; }
                lv = v[0]; ls = 0;
#pragma unroll
                for (int i = 1; i < 16; ++i) { if (v[i] < lv) { lv = v[i]; ls = i; } }
                lm = lane + (ls << 6);
            }
        }
    }
    const int jbase = (b * N_ + n0) * 9;
    if (tid < 16 * 9) out_dst[jbase + tid] = (jbase + tid) / 9;
}

extern "C" void kernel_launch(void* const* d_in, const int* in_sizes, int n_in,
                              void* d_out, int out_size, void* d_ws, size_t ws_size,
                              hipStream_t stream) {
    (void)in_sizes; (void)n_in; (void)out_size;
    const float* X = (const float*)d_in[0];
    int* out = (int*)d_out;
    const size_t xt_bytes  = (size_t)B_ * N_ * C_ * 2;   // 33,554,432
    const size_t nrm_bytes = (size_t)B_ * N_ * 4;        // 262,144
    if (ws_size >= xt_bytes + nrm_bytes) {
        unsigned short* XT = (unsigned short*)d_ws;
        u32* NRMU = (u32*)((char*)d_ws + xt_bytes);
        hipMemsetAsync(NRMU, 0, nrm_bytes, stream);      // zero norm accumulators
        trans_kernel<<<dim3(B_ * 16), dim3(256), 0, stream>>>(X, XT, NRMU);
        knn_mfma_kernel<<<dim3(B_ * 16), dim3(256), 0, stream>>>(XT, NRMU, out);
    } else {
        knn_kernel<<<dim3(B_ * 64), dim3(256), 0, stream>>>(X, out);
    }
}